// Round 4
// baseline (649.553 us; speedup 1.0000x reference)
//
#include <hip/hip_runtime.h>
#include <math.h>

#define PI_F 3.14159265358979323846f
// swizzles: XOR bank-index bits with higher address bits (bijective, both sides)
#define SWZ16(i) ((i) ^ (((i) >> 4) & 15))  // 4-bit XOR: full odd/even bank spread
#define SWZ8(i)  ((i) ^ (((i) >> 3) & 7))   // used for Wd tile in down-proj phase

// ---------------- Kernel 0: build circular-conv tables from complex spectral weights --
// KK[a][b][c] = (1/S^2) * sum_{u<S, v<=S/2} m_v * ( wr*cos(2pi(ua+vb)/S) - wi*sin(...) )
__global__ __launch_bounds__(256) void build_tables(
    const float* __restrict__ cw_x, const float* __restrict__ cw_z,
    float* __restrict__ KKx, float* __restrict__ KKz)
{
    int tid = blockIdx.x * 256 + threadIdx.x;
    if (tid < 2048) {                    // X branch: S=16, V=9
        int c = tid & 7;
        int ab = tid >> 3;               // a*16+b
        int a = ab >> 4, b = ab & 15;
        float acc = 0.f;
        for (int u = 0; u < 16; ++u) {
            for (int v = 0; v < 9; ++v) {
                float m = (v == 0 || v == 8) ? 1.f : 2.f;
                int ph = (u * a + v * b) & 15;
                float th = (2.f * PI_F / 16.f) * (float)ph;
                float sn, cs;
                sincosf(th, &sn, &cs);
                const float* wp = cw_x + (size_t)((u * 9 + v) * 8 + c) * 2;
                acc += m * (wp[0] * cs - wp[1] * sn);
            }
        }
        KKx[ab * 8 + c] = acc * (1.f / 256.f);
    } else if (tid < 2048 + 512) {       // Z branch: S=8, V=5
        int e = tid - 2048;
        int c = e & 7;
        int ab = e >> 3;                 // a*8+b
        int a = ab >> 3, b = ab & 7;
        float acc = 0.f;
        for (int u = 0; u < 8; ++u) {
            for (int v = 0; v < 5; ++v) {
                float m = (v == 0 || v == 4) ? 1.f : 2.f;
                int ph = (u * a + v * b) & 7;
                float th = (2.f * PI_F / 8.f) * (float)ph;
                float sn, cs;
                sincosf(th, &sn, &cs);
                const float* wp = cw_z + (size_t)((u * 5 + v) * 8 + c) * 2;
                acc += m * (wp[0] * cs - wp[1] * sn);
            }
        }
        KKz[ab * 8 + c] = acc * (1.f / 64.f);
    }
}

// ---------------- Fused kernel: down-proj -> branch -> up-proj, one block per batch ---
// 256 blocks x 1024 threads (16 waves/CU; __launch_bounds__(1024,4) pins VGPR<=128).
// Local rows 0..63 = Z tokens, 64..319 = X tokens (matches cat concat order).
// Phase 1: h into LDS. 64 groups x 16 lanes, 5 rows/group; 16 waves give ~4x the
//          in-flight load bytes vs R3 (latency-hiding fix: 3.8KB -> ~15KB/CU).
// Phase 2: LN1 -> circular conv (swizzled LDS) -> LN2 -> MLP -> catS (t<320 active).
// Phase 3: up-proj; 16 waves x 20 rows, lane owns 3 f4-cols -> 1KB coalesced stores.
__global__ __launch_bounds__(1024, 4) void fused_kernel(
    const float* __restrict__ x, const float* __restrict__ Wd,
    const float* __restrict__ bd,
    const float* __restrict__ KKx, const float* __restrict__ KKz,
    const float* __restrict__ g1v, const float* __restrict__ b1v,
    const float* __restrict__ g2v, const float* __restrict__ b2v,
    const float* __restrict__ W1, const float* __restrict__ b1m,
    const float* __restrict__ W2, const float* __restrict__ b2m,
    const float* __restrict__ Wu, const float* __restrict__ bu,
    float* __restrict__ out)
{
    __shared__ float4 wds[1536];      // 24KB  Wd swizzled
    __shared__ float  hSf[320 * 9];   // 11.25KB  h rows, stride 9 (conflict-free)
    __shared__ float4 kkx[512];       // 8KB   X conv table
    __shared__ float4 kkz[128];       // 2KB   Z conv table
    __shared__ float4 t1x[512];       // 8KB   X t1 tile (swizzled)
    __shared__ float4 t1z[128];       // 2KB   Z t1 tile (swizzled)
    __shared__ float  catS[320 * 9];  // 11.25KB cat rows, stride 9
    __shared__ float  sW1[128], sW2[128], sB1[16], sB2[8];
    __shared__ float  sG1[8], sH1[8], sG2[8], sH2[8];

    int t = threadIdx.x;
    int bid = blockIdx.x;

    // ---- stage Wd, tables, params (spread across thread ranges) ----
    const float4* Wd4 = (const float4*)Wd;
    for (int i = t; i < 1536; i += 1024) wds[SWZ8(i)] = Wd4[i];
    if (t < 512)       kkx[t] = ((const float4*)KKx)[t];
    else if (t < 640)  kkz[t - 512] = ((const float4*)KKz)[t - 512];
    else if (t < 768)  sW1[t - 640] = W1[t - 640];
    else if (t < 896)  sW2[t - 768] = W2[t - 768];
    else if (t < 912)  sB1[t - 896] = b1m[t - 896];
    else if (t < 920)  sB2[t - 912] = b2m[t - 912];
    else if (t < 928)  sG1[t - 920] = g1v[t - 920];
    else if (t < 936)  sH1[t - 928] = b1v[t - 928];
    else if (t < 944)  sG2[t - 936] = g2v[t - 936];
    else if (t < 952)  sH2[t - 944] = b2v[t - 944];
    float bdv[8];
    #pragma unroll
    for (int c = 0; c < 8; ++c) bdv[c] = bd[c];   // uniform -> SGPR loads
    __syncthreads();

    // ---- phase 1: h = x @ Wd + bd for this block's 320 rows, into hSf ----
    {
        int g = t >> 4;                  // 64 groups of 16 lanes
        int l = t & 15;
        const float4* xr = (const float4*)x + ((size_t)bid * 320 + g * 5) * 192;
        float acc[5][8];
        #pragma unroll
        for (int r = 0; r < 5; ++r)
            #pragma unroll
            for (int c = 0; c < 8; ++c) acc[r][c] = 0.f;
        #pragma unroll
        for (int j = 0; j < 12; ++j) {
            float4 v[5];
            #pragma unroll
            for (int r = 0; r < 5; ++r) v[r] = xr[(size_t)r * 192 + l + 16 * j];
            #pragma unroll
            for (int e = 0; e < 4; ++e) {
                int f4i = ((l + 16 * j) * 4 + e) * 2;        // even
                int sw = SWZ8(f4i);
                float4 w0 = wds[sw];
                float4 w1 = wds[sw ^ 1];                     // SWZ8(f4i+1)==SWZ8(f4i)^1
                #pragma unroll
                for (int r = 0; r < 5; ++r) {
                    float xv = (e == 0) ? v[r].x : (e == 1) ? v[r].y : (e == 2) ? v[r].z : v[r].w;
                    acc[r][0] += xv * w0.x;  acc[r][1] += xv * w0.y;
                    acc[r][2] += xv * w0.z;  acc[r][3] += xv * w0.w;
                    acc[r][4] += xv * w1.x;  acc[r][5] += xv * w1.y;
                    acc[r][6] += xv * w1.z;  acc[r][7] += xv * w1.w;
                }
            }
        }
        #pragma unroll
        for (int off = 1; off < 16; off <<= 1)
            #pragma unroll
            for (int r = 0; r < 5; ++r)
                #pragma unroll
                for (int c = 0; c < 8; ++c)
                    acc[r][c] += __shfl_xor(acc[r][c], off, 64);
        if (l < 5) {
            float o[8];
            #pragma unroll
            for (int c = 0; c < 8; ++c)
                o[c] = (l == 0) ? acc[0][c] : (l == 1) ? acc[1][c] :
                       (l == 2) ? acc[2][c] : (l == 3) ? acc[3][c] : acc[4][c];
            int lr = g * 5 + l;
            #pragma unroll
            for (int c = 0; c < 8; ++c) hSf[lr * 9 + c] = o[c] + bdv[c];
        }
    }
    __syncthreads();

    // ---- phase 2: LN1 -> conv -> LN2 -> MLP -> catS (threads 0..319 active) ----
    bool active = (t < 320);
    bool isX = (t < 256);
    int lr = isX ? (64 + t) : (t - 256);
    float raw[8];
    if (active) {
        #pragma unroll
        for (int c = 0; c < 8; ++c) raw[c] = hSf[lr * 9 + c];

        float mean = 0.f;
        #pragma unroll
        for (int c = 0; c < 8; ++c) mean += raw[c];
        mean *= 0.125f;
        float var = 0.f;
        #pragma unroll
        for (int c = 0; c < 8; ++c) { float d = raw[c] - mean; var += d * d; }
        var *= 0.125f;
        float inv = rsqrtf(var + 1e-5f);
        float t1[8];
        #pragma unroll
        for (int c = 0; c < 8; ++c) t1[c] = (raw[c] - mean) * inv * sG1[c] + sH1[c];

        if (isX) {
            int i0 = 2 * t;
            t1x[SWZ16(i0)]     = make_float4(t1[0], t1[1], t1[2], t1[3]);
            t1x[SWZ16(i0 + 1)] = make_float4(t1[4], t1[5], t1[6], t1[7]);
        } else {
            int tz = t - 256;
            int i0 = 2 * tz;
            t1z[SWZ16(i0)]     = make_float4(t1[0], t1[1], t1[2], t1[3]);
            t1z[SWZ16(i0 + 1)] = make_float4(t1[4], t1[5], t1[6], t1[7]);
        }
    }
    __syncthreads();

    if (active) {
        float s0=0.f,s1=0.f,s2=0.f,s3=0.f,s4=0.f,s5=0.f,s6=0.f,s7=0.f;
        if (isX) {
            int p = t >> 4, q = t & 15;
            for (int da = 0; da < 16; ++da) {
                int qp = (q - da) & 15;
                #pragma unroll
                for (int db = 0; db < 16; ++db) {
                    int pp = (p - db) & 15;
                    int si = (pp * 16 + qp) * 2;            // even
                    int sw = SWZ16(si);
                    float4 v0 = t1x[sw];
                    float4 v1 = t1x[sw ^ 1];                // SWZ16(si+1)==SWZ16(si)^1
                    int kb = (da * 16 + db) * 2;
                    float4 k0 = kkx[kb], k1 = kkx[kb + 1];  // uniform addr -> broadcast
                    s0 += k0.x * v0.x;  s1 += k0.y * v0.y;
                    s2 += k0.z * v0.z;  s3 += k0.w * v0.w;
                    s4 += k1.x * v1.x;  s5 += k1.y * v1.y;
                    s6 += k1.z * v1.z;  s7 += k1.w * v1.w;
                }
            }
        } else {
            int tz = t - 256;
            int p = tz >> 3, q = tz & 7;
            for (int da = 0; da < 8; ++da) {
                int qp = (q - da) & 7;
                #pragma unroll
                for (int db = 0; db < 8; ++db) {
                    int pp = (p - db) & 7;
                    int si = (pp * 8 + qp) * 2;             // even
                    int sw = SWZ16(si);
                    float4 v0 = t1z[sw];
                    float4 v1 = t1z[sw ^ 1];
                    int kb = (da * 8 + db) * 2;
                    float4 k0 = kkz[kb], k1 = kkz[kb + 1];
                    s0 += k0.x * v0.x;  s1 += k0.y * v0.y;
                    s2 += k0.z * v0.z;  s3 += k0.w * v0.w;
                    s4 += k1.x * v1.x;  s5 += k1.y * v1.y;
                    s6 += k1.z * v1.z;  s7 += k1.w * v1.w;
                }
            }
        }

        float sarr[8] = {s0, s1, s2, s3, s4, s5, s6, s7};
        float m2 = 0.f;
        #pragma unroll
        for (int c = 0; c < 8; ++c) m2 += sarr[c];
        m2 *= 0.125f;
        float v2 = 0.f;
        #pragma unroll
        for (int c = 0; c < 8; ++c) { float d = sarr[c] - m2; v2 += d * d; }
        v2 *= 0.125f;
        float inv2 = rsqrtf(v2 + 1e-5f);
        float t2[8];
        #pragma unroll
        for (int c = 0; c < 8; ++c) t2[c] = (sarr[c] - m2) * inv2 * sG2[c] + sH2[c];

        float hm[16];
        #pragma unroll
        for (int j = 0; j < 16; ++j) {
            float acc = sB1[j];
            #pragma unroll
            for (int c = 0; c < 8; ++c) acc += t2[c] * sW1[c * 16 + j];
            hm[j] = 0.5f * acc * (1.f + erff(acc * 0.70710678118654752f));  // exact GELU
        }
        #pragma unroll
        for (int c = 0; c < 8; ++c) {
            float acc = sB2[c];
            #pragma unroll
            for (int j = 0; j < 16; ++j) acc += hm[j] * sW2[j * 8 + c];
            catS[lr * 9 + c] = acc + raw[c];
        }
    }
    __syncthreads();

    // ---- phase 3: out = cat @ Wu + bu ; 16 waves x 20 rows, lane owns 3 f4-cols ----
    {
        int wv = t >> 6;                 // 0..15
        int ln = t & 63;
        const float4* Wu4 = (const float4*)Wu;
        float4 wr[24];                   // [c*3+k]
        #pragma unroll
        for (int c = 0; c < 8; ++c)
            #pragma unroll
            for (int k = 0; k < 3; ++k)
                wr[c * 3 + k] = Wu4[c * 192 + ln + 64 * k];
        float4 bv[3];
        #pragma unroll
        for (int k = 0; k < 3; ++k) bv[k] = ((const float4*)bu)[ln + 64 * k];

        #pragma unroll 4
        for (int r = 0; r < 20; ++r) {
            int lrow = wv * 20 + r;
            float cv[8];
            #pragma unroll
            for (int c = 0; c < 8; ++c) cv[c] = catS[lrow * 9 + c];  // broadcast
            float4* o4 = (float4*)out + ((size_t)bid * 320 + lrow) * 192 + ln;
            #pragma unroll
            for (int k = 0; k < 3; ++k) {
                float4 a = bv[k];
                #pragma unroll
                for (int c = 0; c < 8; ++c) {
                    a.x += cv[c] * wr[c * 3 + k].x;
                    a.y += cv[c] * wr[c * 3 + k].y;
                    a.z += cv[c] * wr[c * 3 + k].z;
                    a.w += cv[c] * wr[c * 3 + k].w;
                }
                o4[64 * k] = a;          // 64 lanes x 16B = 1KB contiguous
            }
        }
    }
}

extern "C" void kernel_launch(void* const* d_in, const int* in_sizes, int n_in,
                              void* d_out, int out_size, void* d_ws, size_t ws_size,
                              hipStream_t stream)
{
    (void)in_sizes; (void)n_in; (void)out_size; (void)ws_size;
    const float* x    = (const float*)d_in[0];
    const float* Wd   = (const float*)d_in[1];
    const float* bd   = (const float*)d_in[2];
    const float* cw_x = (const float*)d_in[3];
    const float* cw_z = (const float*)d_in[4];
    const float* g1   = (const float*)d_in[5];
    const float* h1   = (const float*)d_in[6];
    const float* g2   = (const float*)d_in[7];
    const float* h2   = (const float*)d_in[8];
    const float* W1   = (const float*)d_in[9];
    const float* b1   = (const float*)d_in[10];
    const float* W2   = (const float*)d_in[11];
    const float* b2   = (const float*)d_in[12];
    const float* Wu   = (const float*)d_in[13];
    const float* bu   = (const float*)d_in[14];
    float* out = (float*)d_out;

    float* KKx = (float*)d_ws;          // 2048 floats
    float* KKz = KKx + 2048;            // 512 floats

    hipLaunchKernelGGL(build_tables, dim3(10), dim3(256), 0, stream, cw_x, cw_z, KKx, KKz);
    hipLaunchKernelGGL(fused_kernel, dim3(256), dim3(1024), 0, stream,
                       x, Wd, bd, KKx, KKz, g1, h1, g2, h2,
                       W1, b1, W2, b2, Wu, bu, out);
}

// Round 5
// 211.656 us; speedup vs baseline: 3.0689x; 3.0689x over previous
//
#include <hip/hip_runtime.h>
#include <math.h>

#define PI_F 3.14159265358979323846f
// swizzles: XOR bank-index bits with higher address bits (bijective, both sides)
#define SWZ16(i) ((i) ^ (((i) >> 4) & 15))  // 4-bit XOR: full odd/even bank spread
#define SWZ8(i)  ((i) ^ (((i) >> 3) & 7))   // used for Wd tile in down-proj phase

// ---------------- Kernel 0: build circular-conv tables from complex spectral weights --
// KK[a][b][c] = (1/S^2) * sum_{u<S, v<=S/2} m_v * ( wr*cos(2pi(ua+vb)/S) - wi*sin(...) )
__global__ __launch_bounds__(256) void build_tables(
    const float* __restrict__ cw_x, const float* __restrict__ cw_z,
    float* __restrict__ KKx, float* __restrict__ KKz)
{
    int tid = blockIdx.x * 256 + threadIdx.x;
    if (tid < 2048) {                    // X branch: S=16, V=9
        int c = tid & 7;
        int ab = tid >> 3;               // a*16+b
        int a = ab >> 4, b = ab & 15;
        float acc = 0.f;
        for (int u = 0; u < 16; ++u) {
            for (int v = 0; v < 9; ++v) {
                float m = (v == 0 || v == 8) ? 1.f : 2.f;
                int ph = (u * a + v * b) & 15;
                float th = (2.f * PI_F / 16.f) * (float)ph;
                float sn, cs;
                sincosf(th, &sn, &cs);
                const float* wp = cw_x + (size_t)((u * 9 + v) * 8 + c) * 2;
                acc += m * (wp[0] * cs - wp[1] * sn);
            }
        }
        KKx[ab * 8 + c] = acc * (1.f / 256.f);
    } else if (tid < 2048 + 512) {       // Z branch: S=8, V=5
        int e = tid - 2048;
        int c = e & 7;
        int ab = e >> 3;                 // a*8+b
        int a = ab >> 3, b = ab & 7;
        float acc = 0.f;
        for (int u = 0; u < 8; ++u) {
            for (int v = 0; v < 5; ++v) {
                float m = (v == 0 || v == 4) ? 1.f : 2.f;
                int ph = (u * a + v * b) & 7;
                float th = (2.f * PI_F / 8.f) * (float)ph;
                float sn, cs;
                sincosf(th, &sn, &cs);
                const float* wp = cw_z + (size_t)((u * 5 + v) * 8 + c) * 2;
                acc += m * (wp[0] * cs - wp[1] * sn);
            }
        }
        KKz[ab * 8 + c] = acc * (1.f / 64.f);
    }
}

// ---------------- Fused kernel: down-proj -> branch -> up-proj, one block per batch ---
// 256 blocks x 512 threads; __launch_bounds__(512,2) -> VGPR cap 256 (NO spill; R4's
// (1024,4) pinned VGPR=64 and spilled acc[][]+wr[24] to scratch: FETCH 210MB->1.1GB).
// 8 waves/CU; per-wave 5x16B loads in flight => ~40KB outstanding/CU (need ~9KB for 6TB/s).
// Local rows 0..63 = Z tokens, 64..319 = X tokens (matches cat concat order).
__global__ __launch_bounds__(512, 2) void fused_kernel(
    const float* __restrict__ x, const float* __restrict__ Wd,
    const float* __restrict__ bd,
    const float* __restrict__ KKx, const float* __restrict__ KKz,
    const float* __restrict__ g1v, const float* __restrict__ b1v,
    const float* __restrict__ g2v, const float* __restrict__ b2v,
    const float* __restrict__ W1, const float* __restrict__ b1m,
    const float* __restrict__ W2, const float* __restrict__ b2m,
    const float* __restrict__ Wu, const float* __restrict__ bu,
    float* __restrict__ out)
{
    __shared__ float4 wds[1536];      // 24KB  Wd swizzled
    __shared__ float  hSf[320 * 9];   // 11.25KB  h rows, stride 9 (conflict-free)
    __shared__ float4 kkx[512];       // 8KB   X conv table
    __shared__ float4 kkz[128];       // 2KB   Z conv table
    __shared__ float4 t1x[512];       // 8KB   X t1 tile (swizzled)
    __shared__ float4 t1z[128];       // 2KB   Z t1 tile (swizzled)
    __shared__ float  catS[320 * 9];  // 11.25KB cat rows, stride 9
    __shared__ float  sW1[128], sW2[128], sB1[16], sB2[8];
    __shared__ float  sG1[8], sH1[8], sG2[8], sH2[8];

    int t = threadIdx.x;
    int bid = blockIdx.x;

    // ---- stage Wd, tables, params (spread across thread ranges) ----
    const float4* Wd4 = (const float4*)Wd;
    #pragma unroll
    for (int i = t; i < 1536; i += 512) wds[SWZ8(i)] = Wd4[i];
    kkx[t] = ((const float4*)KKx)[t];                  // all 512 threads
    if (t < 128)       kkz[t] = ((const float4*)KKz)[t];
    else if (t < 256)  sW1[t - 128] = W1[t - 128];
    else if (t < 384)  sW2[t - 256] = W2[t - 256];
    else if (t < 400)  sB1[t - 384] = b1m[t - 384];
    else if (t < 408)  sB2[t - 400] = b2m[t - 400];
    else if (t < 416)  sG1[t - 408] = g1v[t - 408];
    else if (t < 424)  sH1[t - 416] = b1v[t - 416];
    else if (t < 432)  sG2[t - 424] = g2v[t - 424];
    else if (t < 440)  sH2[t - 432] = b2v[t - 432];
    float bdv[8];
    #pragma unroll
    for (int c = 0; c < 8; ++c) bdv[c] = bd[c];        // uniform -> scalar loads
    __syncthreads();

    // ---- phase 1: h = x @ Wd + bd for this block's 320 rows, into hSf ----
    {
        int g = t >> 4;                  // 32 groups of 16 lanes
        int l = t & 15;
        const float4* x4 = (const float4*)x;
        #pragma unroll
        for (int p = 0; p < 2; ++p) {
            int lr0 = g * 10 + p * 5;    // local rows lr0..lr0+4
            const float4* xr = x4 + ((size_t)bid * 320 + lr0) * 192;
            float acc[5][8];
            #pragma unroll
            for (int r = 0; r < 5; ++r)
                #pragma unroll
                for (int c = 0; c < 8; ++c) acc[r][c] = 0.f;
            #pragma unroll
            for (int j = 0; j < 12; ++j) {
                float4 v[5];
                #pragma unroll
                for (int r = 0; r < 5; ++r) v[r] = xr[(size_t)r * 192 + l + 16 * j];
                #pragma unroll
                for (int e = 0; e < 4; ++e) {
                    int f4i = ((l + 16 * j) * 4 + e) * 2;        // even
                    int sw = SWZ8(f4i);
                    float4 w0 = wds[sw];
                    float4 w1 = wds[sw ^ 1];                     // SWZ8(f4i+1)==SWZ8(f4i)^1
                    #pragma unroll
                    for (int r = 0; r < 5; ++r) {
                        float xv = (e == 0) ? v[r].x : (e == 1) ? v[r].y : (e == 2) ? v[r].z : v[r].w;
                        acc[r][0] += xv * w0.x;  acc[r][1] += xv * w0.y;
                        acc[r][2] += xv * w0.z;  acc[r][3] += xv * w0.w;
                        acc[r][4] += xv * w1.x;  acc[r][5] += xv * w1.y;
                        acc[r][6] += xv * w1.z;  acc[r][7] += xv * w1.w;
                    }
                }
            }
            #pragma unroll
            for (int off = 1; off < 16; off <<= 1)
                #pragma unroll
                for (int r = 0; r < 5; ++r)
                    #pragma unroll
                    for (int c = 0; c < 8; ++c)
                        acc[r][c] += __shfl_xor(acc[r][c], off, 64);
            if (l < 5) {
                float o[8];
                #pragma unroll
                for (int c = 0; c < 8; ++c)
                    o[c] = (l == 0) ? acc[0][c] : (l == 1) ? acc[1][c] :
                           (l == 2) ? acc[2][c] : (l == 3) ? acc[3][c] : acc[4][c];
                int lr = lr0 + l;
                #pragma unroll
                for (int c = 0; c < 8; ++c) hSf[lr * 9 + c] = o[c] + bdv[c];
            }
        }
    }
    __syncthreads();

    // ---- phase 2: LN1 -> conv -> LN2 -> MLP -> catS (threads 0..319 active) ----
    bool active = (t < 320);
    bool isX = (t < 256);
    int lr = isX ? (64 + t) : (t - 256);
    float raw[8];
    if (active) {
        #pragma unroll
        for (int c = 0; c < 8; ++c) raw[c] = hSf[lr * 9 + c];

        float mean = 0.f;
        #pragma unroll
        for (int c = 0; c < 8; ++c) mean += raw[c];
        mean *= 0.125f;
        float var = 0.f;
        #pragma unroll
        for (int c = 0; c < 8; ++c) { float d = raw[c] - mean; var += d * d; }
        var *= 0.125f;
        float inv = rsqrtf(var + 1e-5f);
        float t1[8];
        #pragma unroll
        for (int c = 0; c < 8; ++c) t1[c] = (raw[c] - mean) * inv * sG1[c] + sH1[c];

        if (isX) {
            int i0 = 2 * t;
            t1x[SWZ16(i0)]     = make_float4(t1[0], t1[1], t1[2], t1[3]);
            t1x[SWZ16(i0 + 1)] = make_float4(t1[4], t1[5], t1[6], t1[7]);
        } else {
            int tz = t - 256;
            int i0 = 2 * tz;
            t1z[SWZ16(i0)]     = make_float4(t1[0], t1[1], t1[2], t1[3]);
            t1z[SWZ16(i0 + 1)] = make_float4(t1[4], t1[5], t1[6], t1[7]);
        }
    }
    __syncthreads();

    if (active) {
        float s0=0.f,s1=0.f,s2=0.f,s3=0.f,s4=0.f,s5=0.f,s6=0.f,s7=0.f;
        if (isX) {
            int p = t >> 4, q = t & 15;
            for (int da = 0; da < 16; ++da) {
                int qp = (q - da) & 15;
                #pragma unroll
                for (int db = 0; db < 16; ++db) {
                    int pp = (p - db) & 15;
                    int si = (pp * 16 + qp) * 2;            // even
                    int sw = SWZ16(si);
                    float4 v0 = t1x[sw];
                    float4 v1 = t1x[sw ^ 1];                // SWZ16(si+1)==SWZ16(si)^1
                    int kb = (da * 16 + db) * 2;
                    float4 k0 = kkx[kb], k1 = kkx[kb + 1];  // uniform addr -> broadcast
                    s0 += k0.x * v0.x;  s1 += k0.y * v0.y;
                    s2 += k0.z * v0.z;  s3 += k0.w * v0.w;
                    s4 += k1.x * v1.x;  s5 += k1.y * v1.y;
                    s6 += k1.z * v1.z;  s7 += k1.w * v1.w;
                }
            }
        } else {
            int tz = t - 256;
            int p = tz >> 3, q = tz & 7;
            for (int da = 0; da < 8; ++da) {
                int qp = (q - da) & 7;
                #pragma unroll
                for (int db = 0; db < 8; ++db) {
                    int pp = (p - db) & 7;
                    int si = (pp * 8 + qp) * 2;             // even
                    int sw = SWZ16(si);
                    float4 v0 = t1z[sw];
                    float4 v1 = t1z[sw ^ 1];
                    int kb = (da * 8 + db) * 2;
                    float4 k0 = kkz[kb], k1 = kkz[kb + 1];
                    s0 += k0.x * v0.x;  s1 += k0.y * v0.y;
                    s2 += k0.z * v0.z;  s3 += k0.w * v0.w;
                    s4 += k1.x * v1.x;  s5 += k1.y * v1.y;
                    s6 += k1.z * v1.z;  s7 += k1.w * v1.w;
                }
            }
        }

        float sarr[8] = {s0, s1, s2, s3, s4, s5, s6, s7};
        float m2 = 0.f;
        #pragma unroll
        for (int c = 0; c < 8; ++c) m2 += sarr[c];
        m2 *= 0.125f;
        float v2 = 0.f;
        #pragma unroll
        for (int c = 0; c < 8; ++c) { float d = sarr[c] - m2; v2 += d * d; }
        v2 *= 0.125f;
        float inv2 = rsqrtf(v2 + 1e-5f);
        float t2[8];
        #pragma unroll
        for (int c = 0; c < 8; ++c) t2[c] = (sarr[c] - m2) * inv2 * sG2[c] + sH2[c];

        float hm[16];
        #pragma unroll
        for (int j = 0; j < 16; ++j) {
            float acc = sB1[j];
            #pragma unroll
            for (int c = 0; c < 8; ++c) acc += t2[c] * sW1[c * 16 + j];
            hm[j] = 0.5f * acc * (1.f + erff(acc * 0.70710678118654752f));  // exact GELU
        }
        #pragma unroll
        for (int c = 0; c < 8; ++c) {
            float acc = sB2[c];
            #pragma unroll
            for (int j = 0; j < 16; ++j) acc += hm[j] * sW2[j * 8 + c];
            catS[lr * 9 + c] = acc + raw[c];
        }
    }
    __syncthreads();

    // ---- phase 3: out = cat @ Wu + bu ; 8 waves x 40 rows, lane owns 3 f4-cols ----
    {
        int wv = t >> 6;                 // 0..7
        int ln = t & 63;
        const float4* Wu4 = (const float4*)Wu;
        float4 wr[24];                   // [c*3+k] = 96 VGPRs (fits 256 budget)
        #pragma unroll
        for (int c = 0; c < 8; ++c)
            #pragma unroll
            for (int k = 0; k < 3; ++k)
                wr[c * 3 + k] = Wu4[c * 192 + ln + 64 * k];
        float4 bv[3];
        #pragma unroll
        for (int k = 0; k < 3; ++k) bv[k] = ((const float4*)bu)[ln + 64 * k];

        #pragma unroll 4
        for (int r = 0; r < 40; ++r) {
            int lrow = wv * 40 + r;
            float cv[8];
            #pragma unroll
            for (int c = 0; c < 8; ++c) cv[c] = catS[lrow * 9 + c];  // broadcast
            float4* o4 = (float4*)out + ((size_t)bid * 320 + lrow) * 192 + ln;
            #pragma unroll
            for (int k = 0; k < 3; ++k) {
                float4 a = bv[k];
                #pragma unroll
                for (int c = 0; c < 8; ++c) {
                    a.x += cv[c] * wr[c * 3 + k].x;
                    a.y += cv[c] * wr[c * 3 + k].y;
                    a.z += cv[c] * wr[c * 3 + k].z;
                    a.w += cv[c] * wr[c * 3 + k].w;
                }
                o4[64 * k] = a;          // 64 lanes x 16B = 1KB contiguous
            }
        }
    }
}

extern "C" void kernel_launch(void* const* d_in, const int* in_sizes, int n_in,
                              void* d_out, int out_size, void* d_ws, size_t ws_size,
                              hipStream_t stream)
{
    (void)in_sizes; (void)n_in; (void)out_size; (void)ws_size;
    const float* x    = (const float*)d_in[0];
    const float* Wd   = (const float*)d_in[1];
    const float* bd   = (const float*)d_in[2];
    const float* cw_x = (const float*)d_in[3];
    const float* cw_z = (const float*)d_in[4];
    const float* g1   = (const float*)d_in[5];
    const float* h1   = (const float*)d_in[6];
    const float* g2   = (const float*)d_in[7];
    const float* h2   = (const float*)d_in[8];
    const float* W1   = (const float*)d_in[9];
    const float* b1   = (const float*)d_in[10];
    const float* W2   = (const float*)d_in[11];
    const float* b2   = (const float*)d_in[12];
    const float* Wu   = (const float*)d_in[13];
    const float* bu   = (const float*)d_in[14];
    float* out = (float*)d_out;

    float* KKx = (float*)d_ws;          // 2048 floats
    float* KKz = KKx + 2048;            // 512 floats

    hipLaunchKernelGGL(build_tables, dim3(10), dim3(256), 0, stream, cw_x, cw_z, KKx, KKz);
    hipLaunchKernelGGL(fused_kernel, dim3(256), dim3(512), 0, stream,
                       x, Wd, bd, KKx, KKz, g1, h1, g2, h2,
                       W1, b1, W2, b2, Wu, bu, out);
}